// Round 1
// baseline (3998.664 us; speedup 1.0000x reference)
//
#include <hip/hip_runtime.h>
#include <hip/hip_bf16.h>

#define DEVI __device__ __forceinline__

DEVI float bf2f(unsigned short u) {
    union { unsigned int i; float f; } x; x.i = ((unsigned int)u) << 16; return x.f;
}
DEVI unsigned short f2bf(float f) {
    union { float f; unsigned int i; } x; x.f = f;
    unsigned int r = x.i + 0x7FFFu + ((x.i >> 16) & 1u);
    return (unsigned short)(r >> 16);
}
DEVI float4 fma4(float s, float4 w, float4 a) {
    a.x = fmaf(s, w.x, a.x); a.y = fmaf(s, w.y, a.y);
    a.z = fmaf(s, w.z, a.z); a.w = fmaf(s, w.w, a.w);
    return a;
}

// ---------------- weight prep ----------------
// enc_w2 (64,64,5,5) -> wT2 [tap][ic][oc=64]
__launch_bounds__(256)
__global__ void prep_wT2_k(const float* __restrict__ src, float* __restrict__ dst) {
    int i = blockIdx.x * 256 + threadIdx.x;            // 25*64*64 = 102400
    int tap = i >> 12; int ic = (i >> 6) & 63; int oc = i & 63;
    dst[i] = src[(oc * 64 + ic) * 25 + tap];
}
// enc_w3 (256,64,5,5) -> wT3 [tap][ic][oc=256]
__launch_bounds__(256)
__global__ void prep_wT3_k(const float* __restrict__ src, float* __restrict__ dst) {
    int i = blockIdx.x * 256 + threadIdx.x;            // 25*64*256 = 409600
    int tap = i >> 14; int rem = i & 16383; int ic = rem >> 8; int oc = rem & 255;
    dst[i] = src[(oc * 64 + ic) * 25 + tap];
}
// dec_w (ICT,64,4,4) -> wd [tap=ky*4+kx][ic][oc=64]
__launch_bounds__(256)
__global__ void prep_wd_k(const float* __restrict__ src, float* __restrict__ dst, int ICT) {
    int i = blockIdx.x * 256 + threadIdx.x;            // 16*ICT*64
    int per = ICT * 64;
    int tap = i / per; int rem = i - tap * per; int ic = rem >> 6; int oc = rem & 63;
    dst[i] = src[(ic * 64 + oc) * 16 + tap];
}
// codebook row norms
__launch_bounds__(256)
__global__ void prep_cbn_k(const float* __restrict__ cb, float* __restrict__ cbn) {
    int row = blockIdx.x * 256 + threadIdx.x;          // 1024
    float s = 0.f;
    for (int c = 0; c < 256; c += 4) {
        float4 v = *(const float4*)&cb[row * 256 + c];
        s = fmaf(v.x, v.x, s); s = fmaf(v.y, v.y, s);
        s = fmaf(v.z, v.z, s); s = fmaf(v.w, v.w, s);
    }
    cbn[row] = s;
}

// ---------------- conv1: 1->64, 5x5, s2, p2, relu ----------------
// x (64,128,128) f32 ; out a1 NHWC (64,64,64,64) f32
__launch_bounds__(256)
__global__ void conv1_k(const float* __restrict__ x, const float* __restrict__ w,
                        const float* __restrict__ b, float* __restrict__ out) {
    int t = blockIdx.x * 256 + threadIdx.x;            // 16777216
    int c = t & 63; int p = t >> 6;
    int ox = p & 63; int oy = (p >> 6) & 63; int n = p >> 12;
    float acc = b[c];
    for (int dy = 0; dy < 5; ++dy) {
        int iy = 2 * oy - 2 + dy;
        if ((unsigned)iy >= 128u) continue;
        for (int dx = 0; dx < 5; ++dx) {
            int ix = 2 * ox - 2 + dx;
            if ((unsigned)ix >= 128u) continue;
            acc = fmaf(x[(n * 128 + iy) * 128 + ix], w[c * 25 + dy * 5 + dx], acc);
        }
    }
    out[t] = fmaxf(acc, 0.f);
}

// ---------------- generic 5x5 conv (fp32, NHWC, IC=64) ----------------
// in NHWC (B,IH,IW,64); wT [25][64][OCT]; out NHWC (B,OH,OW,OCT)
template<int S, int OCT>
__launch_bounds__(256)
__global__ void conv5x5_k(const float* __restrict__ in, const float* __restrict__ wT,
                          const float* __restrict__ bias, float* __restrict__ out,
                          int IH, int IW, int OH, int OW, int do_relu) {
    constexpr int PATCH = 7 * S + 5;
    constexpr int RST = PATCH * 16 + 4;    // +4 words: break bank aliasing of pixel groups
    constexpr int OCB = OCT / 64;
    __shared__ float patch[PATCH * RST];
    __shared__ float Wl[16 * 64];

    int bi = blockIdx.x;
    int ocb = bi % OCB; int rest = bi / OCB;
    int tw = OW >> 3, th = OH >> 3;
    int txi = rest % tw; rest /= tw;
    int tyi = rest % th; int n = rest / th;
    int oy0 = tyi << 3, ox0 = txi << 3;
    int t = threadIdx.x;
    int oc4 = (t & 15) << 2;
    int pg = t >> 4;
    int ppy = pg >> 1;
    int ppx = (pg & 1) << 2;

    float4 acc[4];
    acc[0] = acc[1] = acc[2] = acc[3] = make_float4(0.f, 0.f, 0.f, 0.f);

    int iy_base = S * oy0 - 2;
    int ix_base = S * ox0 - 2;

    for (int icc = 0; icc < 4; ++icc) {
        int ic0 = icc << 4;
        __syncthreads();
        for (int i = t; i < PATCH * PATCH * 4; i += 256) {
            int pix = i >> 2, c4 = (i & 3) << 2;
            int py = pix / PATCH, px = pix - py * PATCH;
            int iy = iy_base + py, ix = ix_base + px;
            float4 v = make_float4(0.f, 0.f, 0.f, 0.f);
            if ((unsigned)iy < (unsigned)IH && (unsigned)ix < (unsigned)IW)
                v = *(const float4*)&in[(((n * IH + iy) * IW + ix) << 6) + ic0 + c4];
            *(float4*)&patch[py * RST + px * 16 + c4] = v;
        }
        for (int tap = 0; tap < 25; ++tap) {
            __syncthreads();
            {
                int icl = t >> 4, o4 = (t & 15) << 2;
                *(float4*)&Wl[icl * 64 + o4] =
                    *(const float4*)&wT[(tap * 64 + ic0 + icl) * OCT + ocb * 64 + o4];
            }
            __syncthreads();
            int dy = tap / 5, dx = tap - 5 * (tap / 5);
            int py = S * ppy + dy;
            int pxb = S * ppx + dx;
            const float* prow = &patch[py * RST];
            #pragma unroll
            for (int ic4 = 0; ic4 < 4; ++ic4) {
                float4 w0 = *(float4*)&Wl[(ic4 * 4 + 0) * 64 + oc4];
                float4 w1 = *(float4*)&Wl[(ic4 * 4 + 1) * 64 + oc4];
                float4 w2 = *(float4*)&Wl[(ic4 * 4 + 2) * 64 + oc4];
                float4 w3 = *(float4*)&Wl[(ic4 * 4 + 3) * 64 + oc4];
                #pragma unroll
                for (int j = 0; j < 4; ++j) {
                    float4 a = *(float4*)&prow[(pxb + S * j) * 16 + ic4 * 4];
                    acc[j] = fma4(a.x, w0, acc[j]);
                    acc[j] = fma4(a.y, w1, acc[j]);
                    acc[j] = fma4(a.z, w2, acc[j]);
                    acc[j] = fma4(a.w, w3, acc[j]);
                }
            }
        }
    }
    float4 bv = *(const float4*)&bias[ocb * 64 + oc4];
    #pragma unroll
    for (int j = 0; j < 4; ++j) {
        float4 v;
        v.x = acc[j].x + bv.x; v.y = acc[j].y + bv.y;
        v.z = acc[j].z + bv.z; v.w = acc[j].w + bv.w;
        if (do_relu) {
            v.x = fmaxf(v.x, 0.f); v.y = fmaxf(v.y, 0.f);
            v.z = fmaxf(v.z, 0.f); v.w = fmaxf(v.w, 0.f);
        }
        int oy = oy0 + ppy, ox = ox0 + ppx + j;
        *(float4*)&out[((n * OH + oy) * OW + ox) * OCT + ocb * 64 + oc4] = v;
    }
}

// ---------------- quantize: argmin + e gather + diff ----------------
// z (65536,256) f32 ; cb (1024,256) ; e bf16 (65536,256) ; diff scalar
__launch_bounds__(256)
__global__ void quantize_k(const float* __restrict__ z, const float* __restrict__ cb,
                           const float* __restrict__ cbn, unsigned short* __restrict__ e,
                           float* __restrict__ diff) {
    __shared__ float zt[16 * 260];
    __shared__ float cd[16 * 257];
    __shared__ int   ci[16 * 257];
    __shared__ float rn[16];
    __shared__ int   widx[16];

    int t = threadIdx.x;
    int row0 = blockIdx.x << 4;
    for (int i = t; i < 1024; i += 256) {
        int r = i >> 6, c4 = (i & 63) << 2;
        *(float4*)&zt[r * 260 + c4] = *(const float4*)&z[(row0 + r) * 256 + c4];
    }
    __syncthreads();
    if (t < 16) {
        float s = 0.f;
        for (int c = 0; c < 256; ++c) { float v = zt[t * 260 + c]; s = fmaf(v, v, s); }
        rn[t] = s;
    }

    float dots[4][16];
    #pragma unroll
    for (int u = 0; u < 4; ++u)
        #pragma unroll
        for (int r = 0; r < 16; ++r) dots[u][r] = 0.f;

    for (int k4 = 0; k4 < 256; k4 += 4) {
        float4 cbv[4];
        #pragma unroll
        for (int u = 0; u < 4; ++u)
            cbv[u] = *(const float4*)&cb[(t + (u << 8)) * 256 + k4];
        #pragma unroll
        for (int r = 0; r < 16; ++r) {
            float4 zv = *(float4*)&zt[r * 260 + k4];
            #pragma unroll
            for (int u = 0; u < 4; ++u) {
                dots[u][r] = fmaf(cbv[u].x, zv.x, dots[u][r]);
                dots[u][r] = fmaf(cbv[u].y, zv.y, dots[u][r]);
                dots[u][r] = fmaf(cbv[u].z, zv.z, dots[u][r]);
                dots[u][r] = fmaf(cbv[u].w, zv.w, dots[u][r]);
            }
        }
    }
    float cn[4];
    #pragma unroll
    for (int u = 0; u < 4; ++u) cn[u] = cbn[t + (u << 8)];
    #pragma unroll
    for (int r = 0; r < 16; ++r) {
        float best = cn[0] - 2.f * dots[0][r]; int bidx = t;
        #pragma unroll
        for (int u = 1; u < 4; ++u) {
            float d = cn[u] - 2.f * dots[u][r];
            if (d < best) { best = d; bidx = t + (u << 8); }
        }
        cd[r * 257 + t] = best;
        ci[r * 257 + t] = bidx;
    }
    __syncthreads();
    if (t < 16) {
        float best = cd[t * 257]; int bidx = ci[t * 257];
        for (int i = 1; i < 256; ++i) {
            float d = cd[t * 257 + i];
            if (d < best) { best = d; bidx = ci[t * 257 + i]; }
        }
        widx[t] = bidx;
        atomicAdd(diff, (rn[t] + best) * (1.f / 16777216.f));
    }
    __syncthreads();
    for (int r = 0; r < 16; ++r) {
        int wi = widx[r];
        e[(row0 + r) * 256 + t] = f2bf(cb[wi * 256 + t]);
    }
}

// ---------------- deconv k4 s2 p1 (per-parity 2x2 conv), relu, bf16 out ----------------
// in bf16 NHWC (B,IH,IW,ICT); wd [16][ICT][64] f32; out bf16 NHWC (B,2IH,2IW,64)
template<int ICT>
__launch_bounds__(256)
__global__ void deconv4x4_k(const unsigned short* __restrict__ in,
                            const float* __restrict__ wd, const float* __restrict__ bias,
                            unsigned short* __restrict__ out, int IH, int IW) {
    constexpr int RST = 148;   // 9*16+4
    __shared__ float patch[9 * RST];
    __shared__ float Wl[16 * 64];

    int bi = blockIdx.x;
    int par = bi & 3; int ry = par >> 1, rx = par & 1;
    int rest = bi >> 2;
    int tw = IW >> 3;
    int txi = rest % tw; rest /= tw;
    int th = IH >> 3;
    int tyi = rest % th; int n = rest / th;
    int a0 = tyi << 3, b0 = txi << 3;
    int by0 = (ry == 0) ? -1 : 0;
    int bx0 = (rx == 0) ? -1 : 0;
    int t = threadIdx.x;
    int oc4 = (t & 15) << 2;
    int pg = t >> 4;
    int ppy = pg >> 1;
    int ppx = (pg & 1) << 2;
    int OH = IH << 1, OW = IW << 1;

    float4 acc[4];
    acc[0] = acc[1] = acc[2] = acc[3] = make_float4(0.f, 0.f, 0.f, 0.f);

    for (int icc = 0; icc < ICT / 16; ++icc) {
        int ic0 = icc << 4;
        __syncthreads();
        for (int i = t; i < 81 * 4; i += 256) {
            int pix = i >> 2, c4 = (i & 3) << 2;
            int pr = pix / 9, pc = pix - pr * 9;
            int ar = a0 + by0 + pr, ac = b0 + bx0 + pc;
            float4 v = make_float4(0.f, 0.f, 0.f, 0.f);
            if ((unsigned)ar < (unsigned)IH && (unsigned)ac < (unsigned)IW) {
                ushort4 u = *(const ushort4*)&in[((n * IH + ar) * IW + ac) * ICT + ic0 + c4];
                v = make_float4(bf2f(u.x), bf2f(u.y), bf2f(u.z), bf2f(u.w));
            }
            *(float4*)&patch[pr * RST + pc * 16 + c4] = v;
        }
        for (int tt = 0; tt < 4; ++tt) {
            int tty = tt >> 1, ttx = tt & 1;
            int ky = 1 - ry + 2 * tty, kx = 1 - rx + 2 * ttx;
            __syncthreads();
            {
                int icl = t >> 4, o4 = (t & 15) << 2;
                *(float4*)&Wl[icl * 64 + o4] =
                    *(const float4*)&wd[((ky * 4 + kx) * ICT + ic0 + icl) * 64 + o4];
            }
            __syncthreads();
            int prr = ppy + 1 - tty;
            int pcb = ppx + 1 - ttx;
            const float* prow = &patch[prr * RST];
            #pragma unroll
            for (int ic4 = 0; ic4 < 4; ++ic4) {
                float4 w0 = *(float4*)&Wl[(ic4 * 4 + 0) * 64 + oc4];
                float4 w1 = *(float4*)&Wl[(ic4 * 4 + 1) * 64 + oc4];
                float4 w2 = *(float4*)&Wl[(ic4 * 4 + 2) * 64 + oc4];
                float4 w3 = *(float4*)&Wl[(ic4 * 4 + 3) * 64 + oc4];
                #pragma unroll
                for (int j = 0; j < 4; ++j) {
                    float4 a = *(float4*)&prow[(pcb + j) * 16 + ic4 * 4];
                    acc[j] = fma4(a.x, w0, acc[j]);
                    acc[j] = fma4(a.y, w1, acc[j]);
                    acc[j] = fma4(a.z, w2, acc[j]);
                    acc[j] = fma4(a.w, w3, acc[j]);
                }
            }
        }
    }
    float4 bv = *(const float4*)&bias[oc4];
    #pragma unroll
    for (int j = 0; j < 4; ++j) {
        float vx = fmaxf(acc[j].x + bv.x, 0.f);
        float vy = fmaxf(acc[j].y + bv.y, 0.f);
        float vz = fmaxf(acc[j].z + bv.z, 0.f);
        float vw = fmaxf(acc[j].w + bv.w, 0.f);
        int oy = ((a0 + ppy) << 1) + ry;
        int ox = ((b0 + ppx + j) << 1) + rx;
        ushort4 o;
        o.x = f2bf(vx); o.y = f2bf(vy); o.z = f2bf(vz); o.w = f2bf(vw);
        *(ushort4*)&out[((n * OH + oy) * OW + ox) * 64 + oc4] = o;
    }
}

// ---------------- final conv 3x3 64->1, p1, tanh ----------------
__launch_bounds__(256)
__global__ void conv3x3_tanh_k(const unsigned short* __restrict__ in,
                               const float* __restrict__ w, const float* __restrict__ b,
                               float* __restrict__ out) {
    __shared__ float ws3[576];
    int t = threadIdx.x;
    for (int i = t; i < 576; i += 256) ws3[i] = w[i];
    __syncthreads();
    int p = blockIdx.x * 256 + t;     // 1048576
    int ox = p & 127, oy = (p >> 7) & 127, n = p >> 14;
    float acc = b[0];
    for (int dy = 0; dy < 3; ++dy) {
        int iy = oy + dy - 1;
        if ((unsigned)iy >= 128u) continue;
        for (int dx = 0; dx < 3; ++dx) {
            int ix = ox + dx - 1;
            if ((unsigned)ix >= 128u) continue;
            const unsigned short* ip = &in[(((n << 7) + iy) * 128 + ix) << 6];
            const float* wp = &ws3[dy * 3 + dx];
            #pragma unroll
            for (int ic = 0; ic < 64; ic += 4) {
                ushort4 u = *(const ushort4*)&ip[ic];
                acc = fmaf(bf2f(u.x), wp[(ic + 0) * 9], acc);
                acc = fmaf(bf2f(u.y), wp[(ic + 1) * 9], acc);
                acc = fmaf(bf2f(u.z), wp[(ic + 2) * 9], acc);
                acc = fmaf(bf2f(u.w), wp[(ic + 3) * 9], acc);
            }
        }
    }
    out[p] = tanhf(acc);
}

extern "C" void kernel_launch(void* const* d_in, const int* in_sizes, int n_in,
                              void* d_out, int out_size, void* d_ws, size_t ws_size,
                              hipStream_t stream) {
    (void)in_sizes; (void)n_in; (void)out_size; (void)ws_size;
    const float* x   = (const float*)d_in[0];
    const float* ew1 = (const float*)d_in[1];
    const float* eb1 = (const float*)d_in[2];
    const float* ew2 = (const float*)d_in[3];
    const float* eb2 = (const float*)d_in[4];
    const float* ew3 = (const float*)d_in[5];
    const float* eb3 = (const float*)d_in[6];
    const float* cb  = (const float*)d_in[7];
    const float* dw1 = (const float*)d_in[8];
    const float* db1 = (const float*)d_in[9];
    const float* dw2 = (const float*)d_in[10];
    const float* db2 = (const float*)d_in[11];
    const float* dw3 = (const float*)d_in[12];
    const float* db3 = (const float*)d_in[13];
    float* out = (float*)d_out;

    float* wsf = (float*)d_ws;
    float* a1 = wsf;                       // NHWC (64,64,64,64) f32
    float* a2 = wsf + 16777216;            // NHWC (64,64,64,64) f32
    float* zz = wsf + 33554432;            // (65536,256) f32
    float* wT2 = wsf + 50331648;           // 25*64*64
    float* wT3 = wT2 + 102400;             // 25*64*256
    float* wd1 = wT3 + 409600;             // 16*256*64
    float* wd2 = wd1 + 262144;             // 16*64*64
    float* cbn = wd2 + 65536;              // 1024
    unsigned short* e  = (unsigned short*)d_ws;   // (65536,256) bf16, overlays dead a1
    unsigned short* y1 = e + 16777216;            // (64,64,64,64) bf16
    unsigned short* y2 = e + 33554432;            // (64,128,128,64) bf16, overlays a2+z

    hipMemsetAsync(out + 1048576, 0, 4, stream);  // diff accumulator

    prep_wT2_k<<<400, 256, 0, stream>>>(ew2, wT2);
    prep_wT3_k<<<1600, 256, 0, stream>>>(ew3, wT3);
    prep_wd_k<<<1024, 256, 0, stream>>>(dw1, wd1, 256);
    prep_wd_k<<<256, 256, 0, stream>>>(dw2, wd2, 64);
    prep_cbn_k<<<4, 256, 0, stream>>>(cb, cbn);

    conv1_k<<<65536, 256, 0, stream>>>(x, ew1, eb1, a1);
    conv5x5_k<1, 64><<<4096, 256, 0, stream>>>(a1, wT2, eb2, a2, 64, 64, 64, 64, 1);
    conv5x5_k<2, 256><<<4096, 256, 0, stream>>>(a2, wT3, eb3, zz, 64, 64, 32, 32, 0);
    quantize_k<<<4096, 256, 0, stream>>>(zz, cb, cbn, e, out + 1048576);
    deconv4x4_k<256><<<4096, 256, 0, stream>>>(e, wd1, db1, y1, 32, 32);
    deconv4x4_k<64><<<16384, 256, 0, stream>>>(y1, wd2, db2, y2, 64, 64);
    conv3x3_tanh_k<<<4096, 256, 0, stream>>>(y2, dw3, db3, out);
}

// Round 2
// 914.808 us; speedup vs baseline: 4.3710x; 4.3710x over previous
//
#include <hip/hip_runtime.h>

typedef _Float16 f16;
typedef _Float16 f16x8 __attribute__((ext_vector_type(8)));
typedef _Float16 f16x4 __attribute__((ext_vector_type(4)));
typedef float f32x4 __attribute__((ext_vector_type(4)));
typedef unsigned short u16;

#define DEVI __device__ __forceinline__

DEVI u16 f2h(float f) { f16 h = (f16)f; return __builtin_bit_cast(u16, h); }
DEVI float h2f(u16 u) { f16 h = __builtin_bit_cast(f16, u); return (float)h; }

// ============================ weight prep ============================
// conv weights (OCT,64,5,5) -> frag-ordered fp16 split planes:
// dst[(((tap*2+icc)*2+pl)*NF + f)*512 + lane*8 + j]
//   = plane_pl( src[(oc*64+ic)*25+tap] ), oc=f*16+(lane&15), ic=icc*32+(lane>>4)*8+j
__launch_bounds__(256)
__global__ void prep_wconv_k(const float* __restrict__ src, u16* __restrict__ dst, int nf_sh) {
    int i = blockIdx.x * 256 + threadIdx.x;
    int j = i & 7, lane = (i >> 3) & 63;
    int q = i >> 9;
    int f = q & ((1 << nf_sh) - 1); q >>= nf_sh;
    int pl = q & 1; q >>= 1;
    int icc = q & 1; int tap = q >> 1;
    int oc = (f << 4) + (lane & 15);
    int ic = icc * 32 + ((lane >> 4) << 3) + j;
    float w = src[(oc * 64 + ic) * 25 + tap];
    if (pl == 0) dst[i] = f2h(w);
    else         dst[i] = f2h((w - h2f(f2h(w))) * 4096.f);
}
// deconv weights (ICT,64,4,4) -> plain fp16 frag order:
// dst[((tap*ICC+icc)*4 + f)*512 + lane*8 + j] = src[(ic*64+oc)*16+tap]
__launch_bounds__(256)
__global__ void prep_wdec_k(const float* __restrict__ src, u16* __restrict__ dst, int icc_sh) {
    int i = blockIdx.x * 256 + threadIdx.x;
    int j = i & 7, lane = (i >> 3) & 63;
    int f = (i >> 9) & 3;
    int q = i >> 11;
    int icc = q & ((1 << icc_sh) - 1); int tap = q >> icc_sh;
    int oc = (f << 4) + (lane & 15);
    int ic = icc * 32 + ((lane >> 4) << 3) + j;
    dst[i] = f2h(src[(ic * 64 + oc) * 16 + tap]);
}
// codebook (1024,256) -> split fp16 frag order:
// dst[((ks*2+pl)*64 + f)*512 + lane*8 + j] = plane(cb[n*256+k]), n=f*16+(lane&15), k=ks*32+(lane>>4)*8+j
__launch_bounds__(256)
__global__ void prep_cb_k(const float* __restrict__ cb, u16* __restrict__ dst) {
    int i = blockIdx.x * 256 + threadIdx.x;   // 524288
    int j = i & 7, lane = (i >> 3) & 63;
    int f = (i >> 9) & 63;
    int q = i >> 15;
    int pl = q & 1; int ks = q >> 1;
    int n = (f << 4) + (lane & 15);
    int k = ks * 32 + ((lane >> 4) << 3) + j;
    float w = cb[n * 256 + k];
    if (pl == 0) dst[i] = f2h(w);
    else         dst[i] = f2h((w - h2f(f2h(w))) * 4096.f);
}
__launch_bounds__(256)
__global__ void prep_cbn_k(const float* __restrict__ cb, float* __restrict__ cbn) {
    int row = blockIdx.x * 256 + threadIdx.x;          // 1024
    float s = 0.f;
    for (int c = 0; c < 256; c += 4) {
        f32x4 v = *(const f32x4*)&cb[row * 256 + c];
        s = fmaf(v.x, v.x, s); s = fmaf(v.y, v.y, s);
        s = fmaf(v.z, v.z, s); s = fmaf(v.w, v.w, s);
    }
    cbn[row] = s;
}

// ============================ conv1: 1->64, 5x5 s2 p2, relu, split-fp16 out ============================
__launch_bounds__(256)
__global__ void conv1_k(const float* __restrict__ x, const float* __restrict__ w,
                        const float* __restrict__ b, u16* __restrict__ oh, u16* __restrict__ ol) {
    __shared__ float wl[25 * 64];
    __shared__ float bl[64];
    int t = threadIdx.x;
    for (int i = t; i < 1600; i += 256) wl[(i % 25) * 64 + i / 25] = w[i];
    if (t < 64) bl[t] = b[t];
    __syncthreads();
    int p = blockIdx.x * 256 + t;                       // 262144 pixels
    int ox = p & 63, oy = (p >> 6) & 63, n = p >> 12;
    f32x4 acc[16];
    #pragma unroll
    for (int c = 0; c < 16; ++c) acc[c] = *(f32x4*)&bl[c * 4];
    for (int dy = 0; dy < 5; ++dy) {
        int iy = 2 * oy - 2 + dy;
        if ((unsigned)iy >= 128u) continue;
        for (int dx = 0; dx < 5; ++dx) {
            int ix = 2 * ox - 2 + dx;
            if ((unsigned)ix >= 128u) continue;
            float v = x[(n * 128 + iy) * 128 + ix];
            const float* wp = &wl[(dy * 5 + dx) * 64];
            #pragma unroll
            for (int c = 0; c < 16; ++c) {
                f32x4 w4 = *(const f32x4*)&wp[c * 4];
                acc[c].x = fmaf(v, w4.x, acc[c].x); acc[c].y = fmaf(v, w4.y, acc[c].y);
                acc[c].z = fmaf(v, w4.z, acc[c].z); acc[c].w = fmaf(v, w4.w, acc[c].w);
            }
        }
    }
    #pragma unroll
    for (int c = 0; c < 16; ++c) {
        ushort4 uh, ul;
        float vv[4] = {acc[c].x, acc[c].y, acc[c].z, acc[c].w};
        u16 rh[4], rl[4];
        #pragma unroll
        for (int k = 0; k < 4; ++k) {
            float v = fmaxf(vv[k], 0.f);
            f16 hh = (f16)v;
            rh[k] = __builtin_bit_cast(u16, hh);
            rl[k] = f2h((v - (float)hh) * 4096.f);
        }
        uh.x = rh[0]; uh.y = rh[1]; uh.z = rh[2]; uh.w = rh[3];
        ul.x = rl[0]; ul.y = rl[1]; ul.z = rl[2]; ul.w = rl[3];
        *(ushort4*)&oh[p * 64 + c * 4] = uh;
        *(ushort4*)&ol[p * 64 + c * 4] = ul;
    }
}

// ============================ split-fp16 MFMA 5x5 conv ============================
// in: split planes NHWC (B,IH,IW,64); wBf frag-ordered; out: split planes NHWC (B,OH,OW,OCT)
template<int S, int OCT, int NI, bool RELU>
__launch_bounds__(256)
__global__ void conv5_k(const u16* __restrict__ Ah_g, const u16* __restrict__ Al_g,
                        const u16* __restrict__ wBf, const float* __restrict__ bias,
                        u16* __restrict__ Oh, u16* __restrict__ Ol,
                        int IH, int IW, int OH, int OW) {
    constexpr int PATCH = 7 * S + 5;
    constexpr int PW = PATCH;
    constexpr int NPIX = PATCH * PATCH;
    constexpr int PLSZ = NPIX * 40;        // 32 ic + 8 pad halfs per pixel
    constexpr int NF = OCT / 16;
    constexpr int BN = NI * 32;
    constexpr int OCB = OCT / BN;
    __shared__ u16 patch[2 * PLSZ];

    int t = threadIdx.x, l = t & 63, wv = t >> 6;
    int wm = wv >> 1, wn = wv & 1, g = l >> 4;

    int bi = blockIdx.x;
    int ocb = bi % OCB; int rest = bi / OCB;
    int tw = OW >> 3, th = OH >> 3;
    int txi = rest % tw; rest /= tw;
    int tyi = rest % th; int n = rest / th;
    int iy0 = S * (tyi << 3) - 2, ix0 = S * (txi << 3) - 2;

    int pb0[2];
    #pragma unroll
    for (int mi = 0; mi < 2; ++mi) {
        int m = wm * 32 + mi * 16 + (l & 15);
        int py = m >> 3, px = m & 7;
        pb0[mi] = ((S * py) * PW + S * px) * 40 + g * 8;
    }

    f32x4 acc0[2][NI], acc1[2][NI];
    f32x4 z4 = {0.f, 0.f, 0.f, 0.f};
    #pragma unroll
    for (int mi = 0; mi < 2; ++mi)
        #pragma unroll
        for (int ni = 0; ni < NI; ++ni) { acc0[mi][ni] = z4; acc1[mi][ni] = z4; }

    for (int icc = 0; icc < 2; ++icc) {
        __syncthreads();
        for (int i = t; i < NPIX * 8; i += 256) {
            int c = i & 3; int r2 = i >> 2;
            int pl = (r2 >= NPIX); int pp = r2 - pl * NPIX;
            int py = pp / PATCH, px = pp - py * PATCH;
            int iy = iy0 + py, ix = ix0 + px;
            uint4 v = make_uint4(0u, 0u, 0u, 0u);
            if ((unsigned)iy < (unsigned)IH && (unsigned)ix < (unsigned)IW)
                v = *(const uint4*)&(pl ? Al_g : Ah_g)[(((n * IH + iy) * IW + ix)) * 64 + icc * 32 + c * 8];
            *(uint4*)&patch[pl * PLSZ + (py * PW + px) * 40 + c * 8] = v;
        }
        __syncthreads();
        for (int tap = 0; tap < 25; ++tap) {
            int dy = tap / 5, dx = tap - 5 * dy;
            int toff = (dy * PW + dx) * 40;
            f16x8 Bh[NI], Bl[NI];
            #pragma unroll
            for (int ni = 0; ni < NI; ++ni) {
                int fg = ocb * (BN / 16) + wn * NI + ni;
                Bh[ni] = *(const f16x8*)&wBf[(size_t)(((tap * 2 + icc) * 2 + 0) * NF + fg) * 512 + l * 8];
                Bl[ni] = *(const f16x8*)&wBf[(size_t)(((tap * 2 + icc) * 2 + 1) * NF + fg) * 512 + l * 8];
            }
            #pragma unroll
            for (int mi = 0; mi < 2; ++mi) {
                f16x8 ah = *(const f16x8*)&patch[pb0[mi] + toff];
                f16x8 al = *(const f16x8*)&patch[PLSZ + pb0[mi] + toff];
                #pragma unroll
                for (int ni = 0; ni < NI; ++ni) {
                    acc0[mi][ni] = __builtin_amdgcn_mfma_f32_16x16x32_f16(ah, Bh[ni], acc0[mi][ni], 0, 0, 0);
                    acc1[mi][ni] = __builtin_amdgcn_mfma_f32_16x16x32_f16(al, Bh[ni], acc1[mi][ni], 0, 0, 0);
                    acc1[mi][ni] = __builtin_amdgcn_mfma_f32_16x16x32_f16(ah, Bl[ni], acc1[mi][ni], 0, 0, 0);
                }
            }
        }
    }
    #pragma unroll
    for (int mi = 0; mi < 2; ++mi)
        #pragma unroll
        for (int ni = 0; ni < NI; ++ni) {
            int oc = ocb * BN + wn * (NI * 16) + ni * 16 + (l & 15);
            float bv = bias[oc];
            #pragma unroll
            for (int reg = 0; reg < 4; ++reg) {
                float v = acc0[mi][ni][reg] + acc1[mi][ni][reg] * (1.f / 4096.f) + bv;
                if (RELU) v = fmaxf(v, 0.f);
                int pix = wm * 32 + mi * 16 + g * 4 + reg;
                int oy = (tyi << 3) + (pix >> 3), ox = (txi << 3) + (pix & 7);
                int idx = ((n * OH + oy) * OW + ox) * OCT + oc;
                f16 hh = (f16)v;
                Oh[idx] = __builtin_bit_cast(u16, hh);
                Ol[idx] = f2h((v - (float)hh) * 4096.f);
            }
        }
}

// ============================ quantize: split-fp16 MFMA dists + exact top-1 ============================
__launch_bounds__(256)
__global__ void quant_k(const u16* __restrict__ zh, const u16* __restrict__ zl,
                        const u16* __restrict__ cbf, const float* __restrict__ cbn,
                        const float* __restrict__ cb, u16* __restrict__ e,
                        float* __restrict__ diff) {
    constexpr int PZ = 264;
    __shared__ u16 zs[2 * 32 * PZ];
    __shared__ float znp[256];
    __shared__ float zn[32];
    __shared__ float rbd[4][32];
    __shared__ int   rbc[4][32];
    __shared__ int   widx[32];

    int t = threadIdx.x, l = t & 63, wv = t >> 6, g = l >> 4;
    int row0 = blockIdx.x * 32;

    for (int i = t; i < 2048; i += 256) {
        int c = i & 31, r = (i >> 5) & 31, pl = i >> 10;
        uint4 v = *(const uint4*)&(pl ? zl : zh)[(row0 + r) * 256 + c * 8];
        *(uint4*)&zs[pl * 32 * PZ + r * PZ + c * 8] = v;
    }
    __syncthreads();
    {
        int r = t >> 3, part = t & 7;
        float s = 0.f;
        for (int k = part * 32; k < part * 32 + 32; ++k) {
            float v = h2f(zs[r * PZ + k]) + h2f(zs[32 * PZ + r * PZ + k]) * (1.f / 4096.f);
            s = fmaf(v, v, s);
        }
        znp[t] = s;
    }
    __syncthreads();
    if (t < 32) {
        float s = 0.f;
        for (int q = 0; q < 8; ++q) s += znp[t * 8 + q];
        zn[t] = s;
    }

    float rd[8]; int rc[8];
    #pragma unroll
    for (int s = 0; s < 8; ++s) { rd[s] = 1e30f; rc[s] = 0; }

    for (int no = 0; no < 8; ++no) {
        int n0 = wv * 256 + no * 32;
        f32x4 acc0[2][2], acc1[2][2];
        f32x4 z4 = {0.f, 0.f, 0.f, 0.f};
        #pragma unroll
        for (int mi = 0; mi < 2; ++mi)
            #pragma unroll
            for (int nf = 0; nf < 2; ++nf) { acc0[mi][nf] = z4; acc1[mi][nf] = z4; }
        for (int ks = 0; ks < 8; ++ks) {
            f16x8 Bh[2], Bl[2];
            #pragma unroll
            for (int nf = 0; nf < 2; ++nf) {
                int fg = (n0 >> 4) + nf;
                Bh[nf] = *(const f16x8*)&cbf[(size_t)((ks * 2 + 0) * 64 + fg) * 512 + l * 8];
                Bl[nf] = *(const f16x8*)&cbf[(size_t)((ks * 2 + 1) * 64 + fg) * 512 + l * 8];
            }
            #pragma unroll
            for (int mi = 0; mi < 2; ++mi) {
                f16x8 ah = *(const f16x8*)&zs[(mi * 16 + (l & 15)) * PZ + ks * 32 + g * 8];
                f16x8 al = *(const f16x8*)&zs[32 * PZ + (mi * 16 + (l & 15)) * PZ + ks * 32 + g * 8];
                #pragma unroll
                for (int nf = 0; nf < 2; ++nf) {
                    acc0[mi][nf] = __builtin_amdgcn_mfma_f32_16x16x32_f16(ah, Bh[nf], acc0[mi][nf], 0, 0, 0);
                    acc1[mi][nf] = __builtin_amdgcn_mfma_f32_16x16x32_f16(al, Bh[nf], acc1[mi][nf], 0, 0, 0);
                    acc1[mi][nf] = __builtin_amdgcn_mfma_f32_16x16x32_f16(ah, Bl[nf], acc1[mi][nf], 0, 0, 0);
                }
            }
        }
        #pragma unroll
        for (int mi = 0; mi < 2; ++mi)
            #pragma unroll
            for (int nf = 0; nf < 2; ++nf) {
                int col = n0 + nf * 16 + (l & 15);
                float cn = cbn[col];
                #pragma unroll
                for (int reg = 0; reg < 4; ++reg) {
                    float d = cn - 2.f * (acc0[mi][nf][reg] + acc1[mi][nf][reg] * (1.f / 4096.f));
                    int slot = mi * 4 + reg;
                    if (d < rd[slot]) { rd[slot] = d; rc[slot] = col; }
                }
            }
    }
    #pragma unroll
    for (int step = 1; step < 16; step <<= 1) {
        #pragma unroll
        for (int s = 0; s < 8; ++s) {
            float od = __shfl_xor(rd[s], step);
            int ocl = __shfl_xor(rc[s], step);
            if (od < rd[s] || (od == rd[s] && ocl < rc[s])) { rd[s] = od; rc[s] = ocl; }
        }
    }
    if ((l & 15) == 0) {
        #pragma unroll
        for (int s = 0; s < 8; ++s) {
            int mi = s >> 2, reg = s & 3;
            int row = mi * 16 + g * 4 + reg;
            rbd[wv][row] = rd[s]; rbc[wv][row] = rc[s];
        }
    }
    __syncthreads();
    if (t < 64) {
        float dval = 0.f;
        if (t < 32) {
            float bd = rbd[0][t]; int bc = rbc[0][t];
            #pragma unroll
            for (int w2 = 1; w2 < 4; ++w2) {
                float od = rbd[w2][t]; int ocl = rbc[w2][t];
                if (od < bd || (od == bd && ocl < bc)) { bd = od; bc = ocl; }
            }
            widx[t] = bc;
            dval = bd + zn[t];
        }
        #pragma unroll
        for (int step = 1; step < 32; step <<= 1) dval += __shfl_xor(dval, step);
        if (t == 0) atomicAdd(diff, dval * (1.f / 16777216.f));
    }
    __syncthreads();
    for (int r = 0; r < 32; ++r) {
        int wi = widx[r];
        e[(row0 + r) * 256 + t] = f2h(cb[wi * 256 + t]);
    }
}

// ============================ plain-fp16 MFMA deconv k4 s2 p1 (per-parity) ============================
template<int ICT>
__launch_bounds__(256)
__global__ void deconv4_k(const u16* __restrict__ in, const u16* __restrict__ wdf,
                          const float* __restrict__ bias, u16* __restrict__ out,
                          int IH, int IW) {
    constexpr int ICC = ICT / 32;
    constexpr int PLSZ = 81 * 40;
    __shared__ u16 patch[PLSZ];

    int t = threadIdx.x, l = t & 63, wv = t >> 6;
    int wm = wv >> 1, wn = wv & 1, g = l >> 4;

    int bi = blockIdx.x;
    int par = bi & 3; int ry = par >> 1, rx = par & 1;
    int rest = bi >> 2;
    int tw = IW >> 3, th = IH >> 3;
    int txi = rest % tw; rest /= tw;
    int tyi = rest % th; int n = rest / th;
    int a0 = tyi << 3, b0 = txi << 3;
    int by0 = ry ? 0 : -1, bx0 = rx ? 0 : -1;
    int OH = IH << 1, OW = IW << 1;

    int pb0[2];
    #pragma unroll
    for (int mi = 0; mi < 2; ++mi) {
        int m = wm * 32 + mi * 16 + (l & 15);
        int pa = m >> 3, pb_ = m & 7;
        pb0[mi] = (pa * 9 + pb_) * 40 + g * 8;
    }

    f32x4 acc[2][2];
    f32x4 z4 = {0.f, 0.f, 0.f, 0.f};
    #pragma unroll
    for (int mi = 0; mi < 2; ++mi)
        #pragma unroll
        for (int ni = 0; ni < 2; ++ni) acc[mi][ni] = z4;

    for (int icc = 0; icc < ICC; ++icc) {
        __syncthreads();
        for (int i = t; i < 324; i += 256) {
            int c = i & 3; int pp = i >> 2;
            int pr = pp / 9, pc = pp - pr * 9;
            int ar = a0 + by0 + pr, ac = b0 + bx0 + pc;
            uint4 v = make_uint4(0u, 0u, 0u, 0u);
            if ((unsigned)ar < (unsigned)IH && (unsigned)ac < (unsigned)IW)
                v = *(const uint4*)&in[((n * IH + ar) * IW + ac) * ICT + icc * 32 + c * 8];
            *(uint4*)&patch[(pr * 9 + pc) * 40 + c * 8] = v;
        }
        __syncthreads();
        #pragma unroll
        for (int tt = 0; tt < 4; ++tt) {
            int tty = tt >> 1, ttx = tt & 1;
            int ky = 1 - ry + 2 * tty, kx = 1 - rx + 2 * ttx;
            int tap = ky * 4 + kx;
            int shift = ((1 - tty) * 9 + (1 - ttx)) * 40;
            f16x8 B[2];
            #pragma unroll
            for (int ni = 0; ni < 2; ++ni)
                B[ni] = *(const f16x8*)&wdf[(size_t)((tap * ICC + icc) * 4 + wn * 2 + ni) * 512 + l * 8];
            #pragma unroll
            for (int mi = 0; mi < 2; ++mi) {
                f16x8 a = *(const f16x8*)&patch[pb0[mi] + shift];
                #pragma unroll
                for (int ni = 0; ni < 2; ++ni)
                    acc[mi][ni] = __builtin_amdgcn_mfma_f32_16x16x32_f16(a, B[ni], acc[mi][ni], 0, 0, 0);
            }
        }
    }
    #pragma unroll
    for (int mi = 0; mi < 2; ++mi)
        #pragma unroll
        for (int ni = 0; ni < 2; ++ni) {
            int oc = wn * 32 + ni * 16 + (l & 15);
            float bv = bias[oc];
            #pragma unroll
            for (int reg = 0; reg < 4; ++reg) {
                float v = fmaxf(acc[mi][ni][reg] + bv, 0.f);
                int pix = wm * 32 + mi * 16 + g * 4 + reg;
                int oy = ((a0 + (pix >> 3)) << 1) + ry;
                int ox = ((b0 + (pix & 7)) << 1) + rx;
                out[((n * OH + oy) * OW + ox) * 64 + oc] = f2h(v);
            }
        }
}

// ============================ final conv 3x3 64->1, p1, tanh ============================
__launch_bounds__(256)
__global__ void conv3x3_tanh_k(const u16* __restrict__ in, const float* __restrict__ w,
                               const float* __restrict__ b, float* __restrict__ out) {
    __shared__ float ws3[576];
    int t = threadIdx.x;
    for (int i = t; i < 576; i += 256) ws3[i] = w[i];
    __syncthreads();
    int p = blockIdx.x * 256 + t;     // 1048576
    int ox = p & 127, oy = (p >> 7) & 127, n = p >> 14;
    float acc = b[0];
    for (int dy = 0; dy < 3; ++dy) {
        int iy = oy + dy - 1;
        if ((unsigned)iy >= 128u) continue;
        for (int dx = 0; dx < 3; ++dx) {
            int ix = ox + dx - 1;
            if ((unsigned)ix >= 128u) continue;
            const u16* ip = &in[(((n << 7) + iy) * 128 + ix) << 6];
            const float* wp = &ws3[dy * 3 + dx];
            #pragma unroll
            for (int ic = 0; ic < 64; ic += 4) {
                f16x4 u = *(const f16x4*)&ip[ic];
                acc = fmaf((float)u.x, wp[(ic + 0) * 9], acc);
                acc = fmaf((float)u.y, wp[(ic + 1) * 9], acc);
                acc = fmaf((float)u.z, wp[(ic + 2) * 9], acc);
                acc = fmaf((float)u.w, wp[(ic + 3) * 9], acc);
            }
        }
    }
    out[p] = tanhf(acc);
}

extern "C" void kernel_launch(void* const* d_in, const int* in_sizes, int n_in,
                              void* d_out, int out_size, void* d_ws, size_t ws_size,
                              hipStream_t stream) {
    (void)in_sizes; (void)n_in; (void)out_size; (void)ws_size;
    const float* x   = (const float*)d_in[0];
    const float* ew1 = (const float*)d_in[1];
    const float* eb1 = (const float*)d_in[2];
    const float* ew2 = (const float*)d_in[3];
    const float* eb2 = (const float*)d_in[4];
    const float* ew3 = (const float*)d_in[5];
    const float* eb3 = (const float*)d_in[6];
    const float* cb  = (const float*)d_in[7];
    const float* dw1 = (const float*)d_in[8];
    const float* db1 = (const float*)d_in[9];
    const float* dw2 = (const float*)d_in[10];
    const float* db2 = (const float*)d_in[11];
    const float* dw3 = (const float*)d_in[12];
    const float* db3 = (const float*)d_in[13];
    float* out = (float*)d_out;

    u16* ws = (u16*)d_ws;
    // region R1 [0, 33554432) halfs: a1 -> z -> (y2 part)
    u16* a1h = ws;             u16* a1l = ws + 16777216;
    u16* zh  = ws;             u16* zl  = ws + 16777216;
    // region R2 [33554432, 67108864): a2 -> e -> (y2 part)
    u16* a2h = ws + 33554432;  u16* a2l = ws + 50331648;
    u16* e   = ws + 33554432;
    // y1 [67108864, 83886080)
    u16* y1  = ws + 67108864;
    // y2 [0, 67108864) : overlays z (dead) and e (dead)
    u16* y2  = ws;
    // weights
    u16* wBf2 = ws + 83886080;          // 204800
    u16* wBf3 = wBf2 + 204800;          // 819200
    u16* wd1f = wBf3 + 819200;          // 262144
    u16* wd2f = wd1f + 262144;          // 65536
    u16* cbf  = wd2f + 65536;           // 524288
    float* cbn = (float*)(cbf + 524288);

    hipMemsetAsync(out + 1048576, 0, 4, stream);  // diff accumulator

    prep_wconv_k<<<800, 256, 0, stream>>>(ew2, wBf2, 2);   // NF=4
    prep_wconv_k<<<3200, 256, 0, stream>>>(ew3, wBf3, 4);  // NF=16
    prep_wdec_k<<<1024, 256, 0, stream>>>(dw1, wd1f, 3);   // ICC=8
    prep_wdec_k<<<256, 256, 0, stream>>>(dw2, wd2f, 1);    // ICC=2
    prep_cb_k<<<2048, 256, 0, stream>>>(cb, cbf);
    prep_cbn_k<<<4, 256, 0, stream>>>(cb, cbn);

    conv1_k<<<1024, 256, 0, stream>>>(x, ew1, eb1, a1h, a1l);
    conv5_k<1, 64, 2, true><<<4096, 256, 0, stream>>>(a1h, a1l, wBf2, eb2, a2h, a2l, 64, 64, 64, 64);
    conv5_k<2, 256, 4, false><<<2048, 256, 0, stream>>>(a2h, a2l, wBf3, eb3, zh, zl, 64, 64, 32, 32);
    quant_k<<<2048, 256, 0, stream>>>(zh, zl, cbf, cbn, cb, e, out + 1048576);
    deconv4_k<256><<<4096, 256, 0, stream>>>(e, wd1f, db1, y1, 32, 32);
    deconv4_k<64><<<16384, 256, 0, stream>>>(y1, wd2f, db2, y2, 64, 64);
    conv3x3_tanh_k<<<4096, 256, 0, stream>>>(y2, dw3, db3, out);
}